// Round 5
// baseline (306.266 us; speedup 1.0000x reference)
//
#include <hip/hip_runtime.h>

#define TSTEPS 365
#define BGRID  20000
#define NMUL   4
#define NEARZERO 1e-6f
#define PF 8            // prefetch ring depth (iterations of forcing in registers)

struct F3 { float p, t, pet; };   // 12B, innermost (.,3) layout

// quad butterfly sum via DPP (pure VALU, no LDS pipe):
// lanes 0..3 of each quad all end with q0+q1+q2+q3 (bitwise-identical:
// fp add is commutative, both stages pair the same operands).
__device__ __forceinline__ float quad_sum(float x) {
    int a = __builtin_amdgcn_update_dpp(0, __float_as_int(x),
                                        0xB1 /*quad_perm(1,0,3,2)*/, 0xF, 0xF, true);
    float s1 = x + __int_as_float(a);
    int b = __builtin_amdgcn_update_dpp(0, __float_as_int(s1),
                                        0x4E /*quad_perm(2,3,0,1)*/, 0xF, 0xF, true);
    return s1 + __int_as_float(b);
}

// thread = b*NMUL + k.  out layout: [ Qsim_avg (T,B) | Qsim (T,B,NMUL) ]  fp32
// amdgpu_waves_per_eu(2,2): the grid supplies only ~1.22 waves/SIMD, so cap the
// backend's occupancy TARGET at 2 (not just the minimum) -> 256-VGPR budget ->
// params + PF ring stay register-resident (rounds 3/4: backend chased 8-wave
// occupancy, remat'ed params and sank the prefetch loads; VGPR_Count 64/44).
__global__ __launch_bounds__(64) __attribute__((amdgpu_waves_per_eu(2, 2)))
void hbv_fwd(
    const float* __restrict__ forcing,   // (T, B, 3)
    const float* __restrict__ pBETA,  const float* __restrict__ pFC,
    const float* __restrict__ pK0,    const float* __restrict__ pK1,
    const float* __restrict__ pK2,    const float* __restrict__ pLP,
    const float* __restrict__ pPERC,  const float* __restrict__ pUZL,
    const float* __restrict__ pTT,    const float* __restrict__ pCFMAX,
    const float* __restrict__ pCFR,   const float* __restrict__ pCWH,
    const float* __restrict__ pBETAET,const float* __restrict__ pC,
    float* __restrict__ out_avg,         // (T, B)
    float* __restrict__ out_q)           // (T, B, NMUL)
{
    const int tid = blockIdx.x * 64 + threadIdx.x;   // grid is exact: 1250*64 = 80000
    const int b = tid >> 2;

    const float parBETA   = pBETA[tid];
    const float parFC     = pFC[tid];
    const float parK0     = pK0[tid];
    const float parK1     = pK1[tid];
    const float parK2     = pK2[tid];
    const float parLP     = pLP[tid];
    const float parPERC   = pPERC[tid];
    const float parUZL    = pUZL[tid];
    const float parTT     = pTT[tid];
    const float parCFMAX  = pCFMAX[tid];
    const float parCFR    = pCFR[tid];
    const float parCWH    = pCWH[tid];
    const float parBETAET = pBETAET[tid];
    const float parC      = pC[tid];

    const float refreeze_coef = parCFR * parCFMAX;
    const float inv_FC   = 1.0f / parFC;
    const float inv_LPFC = 1.0f / (parLP * parFC);

    float snow = NEARZERO, melt = 0.0f, sm = 0.0f, suz = 0.0f, slz = 0.0f;

    const F3* __restrict__ f3 = (const F3*)forcing;

    unsigned fofs  = (unsigned)b;            // into f3, stride BGRID per t
    unsigned qqofs = (unsigned)tid;          // into out_q, stride BGRID*NMUL
    unsigned qaofs = (unsigned)b;            // into out_avg, stride BGRID

    // --- fill prefetch ring ------------------------------------------------
    F3 buf[PF];
#pragma unroll
    for (int i = 0; i < PF; ++i) { buf[i] = f3[fofs]; fofs += BGRID; }
    // fofs now points at t = PF

    auto step = [&](const F3 fv) {
        const float p   = fv.p;
        const float tv  = fv.t;
        const float pet = fv.pet;

        // snow module
        const float temp_diff = tv - parTT;
        const bool  is_rain = temp_diff > 0.0f;
        const float rain       = is_rain ? p : 0.0f;
        const float snow_input = is_rain ? 0.0f : p;
        float snow1 = snow + snow_input;
        const float pot_melt = parCFMAX * fmaxf(temp_diff, 0.0f);
        const float melt_amount = fminf(pot_melt, snow1);
        snow1 -= melt_amount;
        float melt1 = melt + melt_amount;
        const float pot_refreeze = refreeze_coef * fmaxf(-temp_diff, 0.0f);
        const float refreeze = fminf(pot_refreeze, melt1);
        snow = snow1 + refreeze;
        melt1 -= refreeze;
        const float tosoil = fmaxf(melt1 - parCWH * snow, 0.0f);
        melt = melt1 - tosoil;

        // soil module (exp2 >= 0 always -> no max(.,0) around pow results;
        // sm1 >= 0 by construction -> no max(.,0) on ef1)
        const float x1 = fmaxf(sm * inv_FC, NEARZERO);
        const float soil_wet = fminf(__builtin_exp2f(parBETA * __log2f(x1)), 1.0f);
        const float rt = rain + tosoil;
        const float recharge = rt * soil_wet;
        float sm1 = sm + rt - recharge;
        const float excess = fmaxf(sm1 - parFC, 0.0f);
        sm1 -= excess;
        const float ef1 = fminf(sm1 * inv_LPFC, 1.0f);
        const float x2 = fmaxf(ef1, NEARZERO);
        const float evapfactor = fminf(__builtin_exp2f(parBETAET * __log2f(x2)), 1.0f);
        const float etact = fminf(pet * evapfactor, sm1);
        const float sm_ae = fmaxf(sm1 - etact, NEARZERO);
        const float sm_ratio = fminf(sm_ae * inv_FC, 1.0f);
        const float capillary = fminf(slz, parC * slz * (1.0f - sm_ratio));
        sm = fmaxf(sm_ae + capillary, NEARZERO);
        float slz1 = fmaxf(slz - capillary, NEARZERO);

        // response routine
        float suz1 = suz + recharge + excess;
        const float perc_flux = fminf(suz1, parPERC);
        suz1 -= perc_flux;
        slz1 += perc_flux;
        const float q0 = parK0 * fmaxf(suz1 - parUZL, 0.0f);
        suz1 -= q0;
        const float q1 = parK1 * suz1;
        suz = suz1 - q1;
        const float q2 = parK2 * slz1;
        slz = slz1 - q2;
        const float q = q0 + q1 + q2;

        out_q[qqofs] = q;
        qqofs += BGRID * NMUL;
        // nmul mean via DPP butterfly; all 4 lanes store the identical value
        // to the same address (coalesced to one line; no exec-mask dance).
        const float qs = quad_sum(q);
        out_avg[qaofs] = qs * 0.25f;
        qaofs += BGRID;
    };

    // --- main: full chunks of PF=8, prefetch always in range (no predicate)
    constexpr int MAINC = ((TSTEPS - PF) / PF) * PF;  // 352 -> bases 0..344
    for (int base = 0; base < MAINC; base += PF) {
#pragma unroll
        for (int j = 0; j < PF; ++j) {
            const F3 fv = buf[j];
            buf[j] = f3[fofs]; fofs += BGRID;   // prefetch t+PF
            step(fv);
        }
    }
    // ring holds t = 352..359; fofs at t=360
#pragma unroll
    for (int j = 0; j < PF; ++j) {
        const F3 fv = buf[j];
        if (j < TSTEPS - MAINC - PF) { buf[j] = f3[fofs]; fofs += BGRID; }
        step(fv);
    }
#pragma unroll
    for (int j = 0; j < TSTEPS - MAINC - PF; ++j) {   // final 5 steps from ring
        step(buf[j]);
    }
}

extern "C" void kernel_launch(void* const* d_in, const int* in_sizes, int n_in,
                              void* d_out, int out_size, void* d_ws, size_t ws_size,
                              hipStream_t stream) {
    // inputs (fp32): 0 forcing, 1 parBETA, 2 parFC, 3 parK0, 4 parK1, 5 parK2,
    // 6 parLP, 7 parPERC, 8 parUZL, 9 parTT, 10 parCFMAX, 11 parCFR, 12 parCWH,
    // 13 parBETAET, 14 parC
    const float* forcing = (const float*)d_in[0];

    float* out_avg = (float*)d_out;                          // (T, B)
    float* out_q   = out_avg + (size_t)TSTEPS * BGRID;       // (T, B, NMUL)

    const int total = BGRID * NMUL;    // 80000
    const int block = 64;              // 1250 single-wave workgroups
    const int grid  = total / block;   // exact: 1250
    hbv_fwd<<<grid, block, 0, stream>>>(forcing,
        (const float*)d_in[1], (const float*)d_in[2], (const float*)d_in[3],
        (const float*)d_in[4], (const float*)d_in[5], (const float*)d_in[6],
        (const float*)d_in[7], (const float*)d_in[8], (const float*)d_in[9],
        (const float*)d_in[10], (const float*)d_in[11], (const float*)d_in[12],
        (const float*)d_in[13], (const float*)d_in[14],
        out_avg, out_q);
}

// Round 6
// 299.990 us; speedup vs baseline: 1.0209x; 1.0209x over previous
//
#include <hip/hip_runtime.h>

#define TSTEPS 365
#define BGRID  20000
#define NMUL   4
#define NEARZERO 1e-6f
#define PF 8            // prefetch ring depth (iterations of forcing in registers)

struct F3 { float p, t, pet; };   // 12B, innermost (.,3) layout

// quad butterfly sum via DPP (pure VALU, no LDS pipe):
// all 4 lanes of a quad end with the identical q0+q1+q2+q3.
__device__ __forceinline__ float quad_sum(float x) {
    int a = __builtin_amdgcn_update_dpp(0, __float_as_int(x),
                                        0xB1 /*quad_perm(1,0,3,2)*/, 0xF, 0xF, true);
    float s1 = x + __int_as_float(a);
    int b = __builtin_amdgcn_update_dpp(0, __float_as_int(s1),
                                        0x4E /*quad_perm(2,3,0,1)*/, 0xF, 0xF, true);
    return s1 + __int_as_float(b);
}

// raw transcendentals: bare v_log_f32 / v_exp_f32, no denormal-guard codegen.
// Domain here: log input >= 1e-6 (normal); exp2 input in [-120, 0] (normal).
__device__ __forceinline__ float fast_log2(float x) { return __builtin_amdgcn_logf(x); }
__device__ __forceinline__ float fast_exp2(float x) { return __builtin_amdgcn_exp2f(x); }

// thread = b*NMUL + k.  out layout: [ Qsim_avg (T,B) | Qsim (T,B,NMUL) ]  fp32
// amdgpu_waves_per_eu(2,2): grid supplies ~1.22 waves/SIMD; capping the
// backend's occupancy target at 2 gives RA a 256-VGPR budget (round 5:
// VGPR 88, ring register-resident — keep).
__global__ __launch_bounds__(64) __attribute__((amdgpu_waves_per_eu(2, 2)))
void hbv_fwd(
    const float* __restrict__ forcing,   // (T, B, 3)
    const float* __restrict__ pBETA,  const float* __restrict__ pFC,
    const float* __restrict__ pK0,    const float* __restrict__ pK1,
    const float* __restrict__ pK2,    const float* __restrict__ pLP,
    const float* __restrict__ pPERC,  const float* __restrict__ pUZL,
    const float* __restrict__ pTT,    const float* __restrict__ pCFMAX,
    const float* __restrict__ pCFR,   const float* __restrict__ pCWH,
    const float* __restrict__ pBETAET,const float* __restrict__ pC,
    float* __restrict__ out_avg,         // (T, B)
    float* __restrict__ out_q)           // (T, B, NMUL)
{
    const int tid = blockIdx.x * 64 + threadIdx.x;   // grid exact: 1250*64 = 80000
    const int b = tid >> 2;

    const float parBETA   = pBETA[tid];
    const float parFC     = pFC[tid];
    const float parK0     = pK0[tid];
    const float parK1     = pK1[tid];
    const float parK2     = pK2[tid];
    const float parLP     = pLP[tid];
    const float parPERC   = pPERC[tid];
    const float parUZL    = pUZL[tid];
    const float parTT     = pTT[tid];
    const float parCFMAX  = pCFMAX[tid];
    const float parCFR    = pCFR[tid];
    const float parCWH    = pCWH[tid];
    const float parBETAET = pBETAET[tid];
    const float parC      = pC[tid];

    const float refreeze_coef = parCFR * parCFMAX;
    const float inv_FC   = 1.0f / parFC;
    const float inv_LPFC = 1.0f / (parLP * parFC);

    float snow = NEARZERO, melt = 0.0f, sm = 0.0f, suz = 0.0f, slz = 0.0f;

    // walked 64-bit pointers (2-instr add/addc per step each, no per-store
    // lshl_add_u64 rematerialization)
    const F3* __restrict__ fp = (const F3*)forcing + b;     // stride BGRID per t
    float* __restrict__ qq = out_q + tid;                    // stride BGRID*NMUL
    float* __restrict__ qa = out_avg + b;                    // stride BGRID

    // --- fill prefetch ring ------------------------------------------------
    F3 buf[PF];
#pragma unroll
    for (int i = 0; i < PF; ++i) { buf[i] = *fp; fp += BGRID; }
    // fp now points at t = PF

    auto step = [&](const F3 fv) {
        const float p   = fv.p;
        const float tv  = fv.t;
        const float pet = fv.pet;

        // snow module
        const float temp_diff = tv - parTT;
        const bool  is_rain = temp_diff > 0.0f;
        const float rain       = is_rain ? p : 0.0f;
        const float snow_input = is_rain ? 0.0f : p;
        float snow1 = snow + snow_input;
        const float pot_melt = parCFMAX * fmaxf(temp_diff, 0.0f);
        const float melt_amount = fminf(pot_melt, snow1);
        snow1 -= melt_amount;
        float melt1 = melt + melt_amount;
        const float pot_refreeze = refreeze_coef * fmaxf(-temp_diff, 0.0f);
        const float refreeze = fminf(pot_refreeze, melt1);
        snow = snow1 + refreeze;
        melt1 -= refreeze;
        const float tosoil = fmaxf(melt1 - parCWH * snow, 0.0f);
        melt = melt1 - tosoil;

        // soil module (raw v_log/v_exp; exp2 >= 0 so no lower clamp on pow;
        // sm1 >= 0 by construction so no lower clamp on ef1)
        const float x1 = fmaxf(sm * inv_FC, NEARZERO);
        const float soil_wet = fminf(fast_exp2(parBETA * fast_log2(x1)), 1.0f);
        const float rt = rain + tosoil;
        const float recharge = rt * soil_wet;
        float sm1 = sm + rt - recharge;
        const float excess = fmaxf(sm1 - parFC, 0.0f);
        sm1 -= excess;
        const float ef1 = fminf(sm1 * inv_LPFC, 1.0f);
        const float x2 = fmaxf(ef1, NEARZERO);
        const float evapfactor = fminf(fast_exp2(parBETAET * fast_log2(x2)), 1.0f);
        const float etact = fminf(pet * evapfactor, sm1);
        const float sm_ae = fmaxf(sm1 - etact, NEARZERO);
        const float sm_ratio = fminf(sm_ae * inv_FC, 1.0f);
        const float capillary = fminf(slz, parC * slz * (1.0f - sm_ratio));
        sm = fmaxf(sm_ae + capillary, NEARZERO);
        float slz1 = fmaxf(slz - capillary, NEARZERO);

        // response routine
        float suz1 = suz + recharge + excess;
        const float perc_flux = fminf(suz1, parPERC);
        suz1 -= perc_flux;
        slz1 += perc_flux;
        const float q0 = parK0 * fmaxf(suz1 - parUZL, 0.0f);
        suz1 -= q0;
        const float q1 = parK1 * suz1;
        suz = suz1 - q1;
        const float q2 = parK2 * slz1;
        slz = slz1 - q2;
        const float q = q0 + q1 + q2;

        *qq = q;
        qq += BGRID * NMUL;
        // nmul mean via DPP; all 4 lanes store identical value to the same
        // address (merged by the coalescer; no exec-mask manipulation).
        const float qs = quad_sum(q);
        *qa = qs * 0.25f;
        qa += BGRID;
    };

    // --- main: full chunks of PF=8, prefetch always in range (no predicate).
    // unroll(disable): keep the outer loop rolled (I-cache).
    constexpr int MAINC = ((TSTEPS - PF) / PF) * PF;  // 352 -> bases 0..344
#pragma clang loop unroll(disable)
    for (int base = 0; base < MAINC; base += PF) {
#pragma unroll
        for (int j = 0; j < PF; ++j) {
            const F3 fv = buf[j];
            buf[j] = *fp; fp += BGRID;          // prefetch t+PF
            step(fv);
        }
    }
    // ring holds t = 352..359; fp at t=360
#pragma unroll
    for (int j = 0; j < PF; ++j) {
        const F3 fv = buf[j];
        if (j < TSTEPS - MAINC - PF) { buf[j] = *fp; fp += BGRID; }
        step(fv);
    }
#pragma unroll
    for (int j = 0; j < TSTEPS - MAINC - PF; ++j) {   // final 5 steps from ring
        step(buf[j]);
    }
}

extern "C" void kernel_launch(void* const* d_in, const int* in_sizes, int n_in,
                              void* d_out, int out_size, void* d_ws, size_t ws_size,
                              hipStream_t stream) {
    // inputs (fp32): 0 forcing, 1 parBETA, 2 parFC, 3 parK0, 4 parK1, 5 parK2,
    // 6 parLP, 7 parPERC, 8 parUZL, 9 parTT, 10 parCFMAX, 11 parCFR, 12 parCWH,
    // 13 parBETAET, 14 parC
    const float* forcing = (const float*)d_in[0];

    float* out_avg = (float*)d_out;                          // (T, B)
    float* out_q   = out_avg + (size_t)TSTEPS * BGRID;       // (T, B, NMUL)

    const int total = BGRID * NMUL;    // 80000
    const int block = 64;              // 1250 single-wave workgroups
    const int grid  = total / block;   // exact: 1250
    hbv_fwd<<<grid, block, 0, stream>>>(forcing,
        (const float*)d_in[1], (const float*)d_in[2], (const float*)d_in[3],
        (const float*)d_in[4], (const float*)d_in[5], (const float*)d_in[6],
        (const float*)d_in[7], (const float*)d_in[8], (const float*)d_in[9],
        (const float*)d_in[10], (const float*)d_in[11], (const float*)d_in[12],
        (const float*)d_in[13], (const float*)d_in[14],
        out_avg, out_q);
}